// Round 6
// baseline (54.076 us; speedup 1.0000x reference)
//
#include <hip/hip_runtime.h>
#include <stdint.h>

// Problem constants (fixed by setup_inputs: bs=8, n=4096, c=256, pool=1024)
#define BATCH 8
#define NPTS  4096
#define CH    256
#define QN    1024

__device__ __forceinline__ float fmul(float a, float b) { return __fmul_rn(a, b); }
__device__ __forceinline__ float fadd(float a, float b) { return __fadd_rn(a, b); }

// reference-exact distance: ((-2*((xx+yy)+zz)) + q_cand) + q_query, no FMA
__device__ __forceinline__ float cdist(const float4 vq, const float4 v) {
  float dot = fadd(fadd(fmul(vq.x, v.x), fmul(vq.y, v.y)), fmul(vq.z, v.z));
  return fadd(fadd(fmul(-2.0f, dot), v.w), vq.w);
}

// order-preserving float->u32 map, idx in low bits -> unique sortable key
__device__ __forceinline__ uint64_t mkkey(float d, uint32_t c) {
  uint32_t bb = __float_as_uint(d);
  bb ^= (uint32_t)((int32_t)bb >> 31) | 0x80000000u;
  return ((uint64_t)bb << 32) | c;
}

__device__ __forceinline__ void cswap(uint64_t& lo, uint64_t& hi) {
  uint64_t mn = hi < lo ? hi : lo;
  uint64_t mx = hi < lo ? lo : hi;
  lo = mn; hi = mx;
}

// wave-min of u64: 4 DPP row_ror steps (VALU pipe) then ^16/^32 via shfl.
__device__ __forceinline__ uint64_t wave_min(uint64_t x) {
#define DPP_MIN_STEP(CTRL)                                                     \
  {                                                                            \
    uint32_t lo = (uint32_t)x, hi = (uint32_t)(x >> 32);                       \
    uint32_t rl = (uint32_t)__builtin_amdgcn_update_dpp((int)lo, (int)lo,      \
                                                        CTRL, 0xF, 0xF, false);\
    uint32_t rh = (uint32_t)__builtin_amdgcn_update_dpp((int)hi, (int)hi,      \
                                                        CTRL, 0xF, 0xF, false);\
    uint64_t o = ((uint64_t)rh << 32) | rl;                                    \
    x = o < x ? o : x;                                                         \
  }
  DPP_MIN_STEP(0x121)  // row_ror:1
  DPP_MIN_STEP(0x122)  // row_ror:2
  DPP_MIN_STEP(0x124)  // row_ror:4
  DPP_MIN_STEP(0x128)  // row_ror:8
#undef DPP_MIN_STEP
  { uint64_t o = (uint64_t)__shfl_xor((long long)x, 16, 64); x = o < x ? o : x; }
  { uint64_t o = (uint64_t)__shfl_xor((long long)x, 32, 64); x = o < x ? o : x; }
  return x;
}

// ---- prep: pack (x,y,z,|v|^2) per point into d_ws (512 KB, L2-resident) ----
__global__ __launch_bounds__(256) void prep_kernel(
    const float* __restrict__ verts,   // [BATCH, NPTS, 3]
    float4*      __restrict__ vc)      // [BATCH*NPTS]
{
  const int p = blockIdx.x * 256 + threadIdx.x;   // 0 .. BATCH*NPTS-1
  const float x = verts[p * 3 + 0];
  const float y = verts[p * 3 + 1];
  const float z = verts[p * 3 + 2];
  const float q = fadd(fadd(fmul(x, x), fmul(y, y)), fmul(z, z));
  vc[p] = make_float4(x, y, z, q);
}

// ---- scan: global-load candidate stream (VMEM pipelining, no LDS) ----
#define SBLOCK 1024
#define SQPB   16                       // 16 waves -> 16 queries per block
#define SBLOCKS_PER_BATCH (QN / SQPB)   // 64 -> grid 512

__global__ __launch_bounds__(SBLOCK, 8) void knn_scan_kernel(
    const float4* __restrict__ vc,     // [BATCH*NPTS] packed candidates
    const int*    __restrict__ sidx,   // [QN]
    int4*         __restrict__ nbr,    // [BATCH*QN] neighbor indices
    float*        __restrict__ outV)   // [BATCH, QN, 3]
{
  const int batch = blockIdx.x / SBLOCKS_PER_BATCH;
  const int qblk  = blockIdx.x % SBLOCKS_PER_BATCH;
  const float4* vb = vc + (size_t)batch * NPTS;

  const int wave = threadIdx.x >> 6;
  const int lane = threadIdx.x & 63;
  const int i = qblk * SQPB + wave;          // query slot in [0, QN)
  const float4 vq = vb[sidx[i]];             // wave-uniform load

  // per-lane top-2 of (d:f32, idx), strict-< insert == lexicographic (d,idx)
  // (idx arrives increasing per lane; strict < keeps older/smaller idx on tie)
  float    d0 = __builtin_inff(), d1 = __builtin_inff();
  uint32_t i0 = 0, i1 = 0;
#pragma unroll 8
  for (int t = 0; t < NPTS / 64; ++t) {
    float4 v = vb[lane + t * 64];            // coalesced dwordx4, L1/L2-hot
    const uint32_t c = lane + t * 64;
    float d = cdist(vq, v);
    bool lt = d < d1;
    d1 = lt ? d : d1;
    i1 = lt ? c : i1;
    bool sw = d1 < d0;
    float    td = d0;  uint32_t ti = i0;
    d0 = sw ? d1 : d0;  i0 = sw ? i1 : i0;
    d1 = sw ? td : d1;  i1 = sw ? ti : i1;
  }

  // wave merge: 5 rounds of "min key strictly greater than prev"
  uint64_t k0 = mkkey(d0, i0);
  uint64_t k1 = mkkey(d1, i1);
  uint64_t prev = 0, nb1 = 0, nb2 = 0, nb3 = 0, nb4 = 0;
#pragma unroll
  for (int r = 0; r < 5; ++r) {
    uint64_t cand = k0 > prev ? k0 : (k1 > prev ? k1 : ~0ull);
    cand = wave_min(cand);
    if (r == 1) nb1 = cand;
    if (r == 2) nb2 = cand;
    if (r == 3) nb3 = cand;
    if (r == 4) nb4 = cand;
    prev = cand;
  }
  // exactness guard: all per-lane drops are > k1; if any lane's k1 < merged
  // 5th, some top-5 member may have been dropped -> exact rescan (~15%/wave)
  if (__any(k1 < nb4)) {
    uint64_t b0 = ~0ull, b1 = ~0ull, b2 = ~0ull, b3 = ~0ull, b4 = ~0ull;
    for (int t = 0; t < NPTS / 64; ++t) {
      float4 v = vb[lane + t * 64];
      uint64_t key = mkkey(cdist(vq, v), lane + t * 64);
      b4 = key < b4 ? key : b4;
      cswap(b3, b4); cswap(b2, b3); cswap(b1, b2); cswap(b0, b1);
    }
    prev = 0;
#pragma unroll
    for (int r = 0; r < 5; ++r) {
      uint64_t cand = b0 > prev ? b0
                    : b1 > prev ? b1
                    : b2 > prev ? b2
                    : b3 > prev ? b3
                    : b4 > prev ? b4 : ~0ull;
      cand = wave_min(cand);
      if (r == 1) nb1 = cand;
      if (r == 2) nb2 = cand;
      if (r == 3) nb3 = cand;
      if (r == 4) nb4 = cand;
      prev = cand;
    }
  }

  if (lane == 0) {
    nbr[(size_t)batch * QN + i] = make_int4((int)(uint32_t)nb1,
                                            (int)(uint32_t)nb2,
                                            (int)(uint32_t)nb3,
                                            (int)(uint32_t)nb4);
  }
  if (lane < 3) {
    float val = lane == 0 ? vq.x : (lane == 1 ? vq.y : vq.z);
    outV[((size_t)batch * QN + i) * 3 + lane] = val;
  }
}

// ---- gather: pure memory burst, 4 queries/block, no LDS ----
#define GBLOCK 256
#define GQPB   (GBLOCK / 64)   // 4 queries per block

__global__ __launch_bounds__(GBLOCK) void knn_gather_kernel(
    const float* __restrict__ feat,    // [BATCH, NPTS, CH]
    const int4*  __restrict__ nbr,     // [BATCH*QN]
    float*       __restrict__ outF)    // [BATCH, QN, CH]
{
  const int gq   = blockIdx.x * GQPB + (threadIdx.x >> 6);  // 0..8191
  const int lane = threadIdx.x & 63;
  const int4 nb  = nbr[gq];            // same addr all lanes -> broadcast
  const int batch = gq >> 10;          // QN = 1024
  const float* fb = feat + (size_t)batch * NPTS * CH;
  const int col = lane * 4;            // 64 lanes * 4 = 256 channels

  float4 f1 = *(const float4*)(fb + (size_t)nb.x * CH + col);
  float4 f2 = *(const float4*)(fb + (size_t)nb.y * CH + col);
  float4 f3 = *(const float4*)(fb + (size_t)nb.z * CH + col);
  float4 f4 = *(const float4*)(fb + (size_t)nb.w * CH + col);
  float4 r;
  r.x = fmaxf(fmaxf(f1.x, f2.x), fmaxf(f3.x, f4.x));
  r.y = fmaxf(fmaxf(f1.y, f2.y), fmaxf(f3.y, f4.y));
  r.z = fmaxf(fmaxf(f1.z, f2.z), fmaxf(f3.z, f4.z));
  r.w = fmaxf(fmaxf(f1.w, f2.w), fmaxf(f3.w, f4.w));
  *(float4*)(outF + (size_t)gq * CH + col) = r;
}

extern "C" void kernel_launch(void* const* d_in, const int* in_sizes, int n_in,
                              void* d_out, int out_size, void* d_ws, size_t ws_size,
                              hipStream_t stream) {
  const float* verts = (const float*)d_in[0];
  const float* feat  = (const float*)d_in[1];
  const int*   sidx  = (const int*)d_in[2];
  float* outV = (float*)d_out;                          // [BATCH, QN, 3]
  float* outF = (float*)d_out + (size_t)BATCH * QN * 3; // [BATCH, QN, CH]

  float4* vc  = (float4*)d_ws;                          // 8*4096*16B = 512 KB
  int4*   nbr = (int4*)((char*)d_ws + (size_t)BATCH * NPTS * sizeof(float4));

  prep_kernel<<<dim3(BATCH * NPTS / 256), dim3(256), 0, stream>>>(verts, vc);
  knn_scan_kernel<<<dim3(BATCH * SBLOCKS_PER_BATCH), dim3(SBLOCK), 0, stream>>>(
      vc, sidx, nbr, outV);
  knn_gather_kernel<<<dim3(BATCH * QN / GQPB), dim3(GBLOCK), 0, stream>>>(
      feat, nbr, outF);
}

// Round 7
// 48.022 us; speedup vs baseline: 1.1261x; 1.1261x over previous
//
#include <hip/hip_runtime.h>
#include <stdint.h>

// Problem constants (fixed by setup_inputs: bs=8, n=4096, c=256, pool=1024)
#define BATCH 8
#define NPTS  4096
#define CH    256
#define QN    1024
#define SUBS  4                  // waves per query (candidate-subset split)
#define SUBN  (NPTS / SUBS)      // 1024 candidates per wave
#define ITERS (SUBN / 64)        // 16 serial iterations per wave

__device__ __forceinline__ float fmul(float a, float b) { return __fmul_rn(a, b); }
__device__ __forceinline__ float fadd(float a, float b) { return __fadd_rn(a, b); }

// reference-exact distance: ((-2*((xx+yy)+zz)) + q_cand) + q_query, no FMA
__device__ __forceinline__ float cdist(const float4 vq, const float4 v) {
  float dot = fadd(fadd(fmul(vq.x, v.x), fmul(vq.y, v.y)), fmul(vq.z, v.z));
  return fadd(fadd(fmul(-2.0f, dot), v.w), vq.w);
}

// order-preserving float->u32 map, idx in low bits -> unique sortable key
__device__ __forceinline__ uint64_t mkkey(float d, uint32_t c) {
  uint32_t bb = __float_as_uint(d);
  bb ^= (uint32_t)((int32_t)bb >> 31) | 0x80000000u;
  return ((uint64_t)bb << 32) | c;
}

__device__ __forceinline__ void cswap(uint64_t& lo, uint64_t& hi) {
  uint64_t mn = hi < lo ? hi : lo;
  uint64_t mx = hi < lo ? lo : hi;
  lo = mn; hi = mx;
}

// wave-min of u64: 4 DPP row_ror steps (VALU pipe) then ^16/^32 via shfl.
__device__ __forceinline__ uint64_t wave_min(uint64_t x) {
#define DPP_MIN_STEP(CTRL)                                                     \
  {                                                                            \
    uint32_t lo = (uint32_t)x, hi = (uint32_t)(x >> 32);                       \
    uint32_t rl = (uint32_t)__builtin_amdgcn_update_dpp((int)lo, (int)lo,      \
                                                        CTRL, 0xF, 0xF, false);\
    uint32_t rh = (uint32_t)__builtin_amdgcn_update_dpp((int)hi, (int)hi,      \
                                                        CTRL, 0xF, 0xF, false);\
    uint64_t o = ((uint64_t)rh << 32) | rl;                                    \
    x = o < x ? o : x;                                                         \
  }
  DPP_MIN_STEP(0x121)  // row_ror:1
  DPP_MIN_STEP(0x122)  // row_ror:2
  DPP_MIN_STEP(0x124)  // row_ror:4
  DPP_MIN_STEP(0x128)  // row_ror:8
#undef DPP_MIN_STEP
  { uint64_t o = (uint64_t)__shfl_xor((long long)x, 16, 64); x = o < x ? o : x; }
  { uint64_t o = (uint64_t)__shfl_xor((long long)x, 32, 64); x = o < x ? o : x; }
  return x;
}

// ---- prep: pack (x,y,z,|v|^2) per point into d_ws (512 KB, L2-resident) ----
__global__ __launch_bounds__(256) void prep_kernel(
    const float* __restrict__ verts,   // [BATCH, NPTS, 3]
    float4*      __restrict__ vc)      // [BATCH*NPTS]
{
  const int p = blockIdx.x * 256 + threadIdx.x;
  const float x = verts[p * 3 + 0];
  const float y = verts[p * 3 + 1];
  const float z = verts[p * 3 + 2];
  const float q = fadd(fadd(fmul(x, x), fmul(y, y)), fmul(z, z));
  vc[p] = make_float4(x, y, z, q);
}

// ---- scan: 4 waves per query, each scans 1024 candidates, writes local
//      top-5 keys to d_ws. No LDS, no __syncthreads. ----
#define SBLOCK 512               // 8 waves/block
// total waves = BATCH*QN*SUBS = 32768 -> grid 4096

__global__ __launch_bounds__(SBLOCK) void knn_scan_kernel(
    const float4* __restrict__ vc,     // [BATCH*NPTS] packed candidates
    const int*    __restrict__ sidx,   // [QN]
    uint64_t*     __restrict__ kbuf,   // [BATCH*QN][SUBS*5] local-top-5 keys
    float*        __restrict__ outV)   // [BATCH, QN, 3]
{
  const int W    = blockIdx.x * (SBLOCK / 64) + (threadIdx.x >> 6);
  const int lane = threadIdx.x & 63;
  const int q    = W >> 2;             // query id 0..8191
  const int s    = W & (SUBS - 1);     // subset id 0..3
  const int batch = q >> 10;           // QN = 1024
  const int iq    = q & (QN - 1);
  const float4* vb = vc + (size_t)batch * NPTS;
  const float4 vq = vb[sidx[iq]];      // wave-uniform load

  // per-lane top-3 of (d:f32, idx), strict-< insert == lexicographic (d,idx)
  // (idx increases per lane; strict < keeps older/smaller idx on equal d)
  float    d0 = __builtin_inff(), d1 = __builtin_inff(), d2 = __builtin_inff();
  uint32_t i0 = 0, i1 = 0, i2 = 0;
#pragma unroll 8
  for (int t = 0; t < ITERS; ++t) {
    const uint32_t c = s * SUBN + t * 64 + lane;
    float4 v = vb[c];
    float d = cdist(vq, v);
    bool lt = d < d2;
    d2 = lt ? d : d2;
    i2 = lt ? c : i2;
    bool s1 = d2 < d1;
    { float td = d1; uint32_t ti = i1;
      d1 = s1 ? d2 : d1;  i1 = s1 ? i2 : i1;
      d2 = s1 ? td : d2;  i2 = s1 ? ti : i2; }
    bool s0 = d1 < d0;
    { float td = d0; uint32_t ti = i0;
      d0 = s0 ? d1 : d0;  i0 = s0 ? i1 : i0;
      d1 = s0 ? td : d1;  i1 = s0 ? ti : i1; }
  }

  // local wave merge: top-5 of this subset (5 rounds of min-key > prev)
  uint64_t k0 = mkkey(d0, i0);
  uint64_t k1 = mkkey(d1, i1);
  uint64_t k2 = mkkey(d2, i2);
  uint64_t prev = 0, l0 = 0, l1 = 0, l2 = 0, l3 = 0, l4 = 0;
#pragma unroll
  for (int r = 0; r < 5; ++r) {
    uint64_t cand = k0 > prev ? k0 : (k1 > prev ? k1 : (k2 > prev ? k2 : ~0ull));
    cand = wave_min(cand);
    if (r == 0) l0 = cand;
    if (r == 1) l1 = cand;
    if (r == 2) l2 = cand;
    if (r == 3) l3 = cand;
    if (r == 4) l4 = cand;
    prev = cand;
  }
  // exactness guard: all per-lane drops are >= that lane's final k2; if every
  // lane's k2 >= local 5th, the local top-5 is exact. False-positive needs
  // >=3 of the subset's top-5 in one lane (~0.25% of waves).
  if (__any(k2 < l4)) {
    uint64_t b0 = ~0ull, b1 = ~0ull, b2 = ~0ull, b3 = ~0ull, b4 = ~0ull;
    for (int t = 0; t < ITERS; ++t) {
      const uint32_t c = s * SUBN + t * 64 + lane;
      uint64_t key = mkkey(cdist(vq, vb[c]), c);
      b4 = key < b4 ? key : b4;
      cswap(b3, b4); cswap(b2, b3); cswap(b1, b2); cswap(b0, b1);
    }
    prev = 0;
#pragma unroll
    for (int r = 0; r < 5; ++r) {
      uint64_t cand = b0 > prev ? b0
                    : b1 > prev ? b1
                    : b2 > prev ? b2
                    : b3 > prev ? b3
                    : b4 > prev ? b4 : ~0ull;
      cand = wave_min(cand);
      if (r == 0) l0 = cand;
      if (r == 1) l1 = cand;
      if (r == 2) l2 = cand;
      if (r == 3) l3 = cand;
      if (r == 4) l4 = cand;
      prev = cand;
    }
  }

  if (lane == 0) {
    uint64_t* kq = kbuf + (size_t)q * (SUBS * 5) + s * 5;
    kq[0] = l0; kq[1] = l1; kq[2] = l2; kq[3] = l3; kq[4] = l4;
  }
  if (s == 0 && lane < 3) {
    float val = lane == 0 ? vq.x : (lane == 1 ? vq.y : vq.z);
    outV[((size_t)batch * QN + iq) * 3 + lane] = val;
  }
}

// ---- gather: merge the 20 subset keys (lanes 0..19), then feature burst ----
#define GBLOCK 256
#define GQPB   (GBLOCK / 64)   // 4 queries per block

__global__ __launch_bounds__(GBLOCK) void knn_gather_kernel(
    const float*    __restrict__ feat,  // [BATCH, NPTS, CH]
    const uint64_t* __restrict__ kbuf,  // [BATCH*QN][SUBS*5]
    float*          __restrict__ outF)  // [BATCH, QN, CH]
{
  const int gq   = blockIdx.x * GQPB + (threadIdx.x >> 6);  // 0..8191
  const int lane = threadIdx.x & 63;

  // global top-5 = top-5 of the union of the 4 subsets' local top-5s
  uint64_t key = lane < SUBS * 5 ? kbuf[(size_t)gq * (SUBS * 5) + lane] : ~0ull;
  uint64_t prev = 0, nb1 = 0, nb2 = 0, nb3 = 0, nb4 = 0;
#pragma unroll
  for (int r = 0; r < 5; ++r) {
    uint64_t cand = key > prev ? key : ~0ull;
    cand = wave_min(cand);
    if (r == 1) nb1 = cand;   // r==0 is self (d=0, global min) -> dropped
    if (r == 2) nb2 = cand;
    if (r == 3) nb3 = cand;
    if (r == 4) nb4 = cand;
    prev = cand;
  }

  const int batch = gq >> 10;          // QN = 1024
  const float* fb = feat + (size_t)batch * NPTS * CH;
  const int col = lane * 4;            // 64 lanes * 4 = 256 channels

  float4 f1 = *(const float4*)(fb + (size_t)(uint32_t)nb1 * CH + col);
  float4 f2 = *(const float4*)(fb + (size_t)(uint32_t)nb2 * CH + col);
  float4 f3 = *(const float4*)(fb + (size_t)(uint32_t)nb3 * CH + col);
  float4 f4 = *(const float4*)(fb + (size_t)(uint32_t)nb4 * CH + col);
  float4 r;
  r.x = fmaxf(fmaxf(f1.x, f2.x), fmaxf(f3.x, f4.x));
  r.y = fmaxf(fmaxf(f1.y, f2.y), fmaxf(f3.y, f4.y));
  r.z = fmaxf(fmaxf(f1.z, f2.z), fmaxf(f3.z, f4.z));
  r.w = fmaxf(fmaxf(f1.w, f2.w), fmaxf(f3.w, f4.w));
  *(float4*)(outF + (size_t)gq * CH + col) = r;
}

extern "C" void kernel_launch(void* const* d_in, const int* in_sizes, int n_in,
                              void* d_out, int out_size, void* d_ws, size_t ws_size,
                              hipStream_t stream) {
  const float* verts = (const float*)d_in[0];
  const float* feat  = (const float*)d_in[1];
  const int*   sidx  = (const int*)d_in[2];
  float* outV = (float*)d_out;                          // [BATCH, QN, 3]
  float* outF = (float*)d_out + (size_t)BATCH * QN * 3; // [BATCH, QN, CH]

  float4*   vc   = (float4*)d_ws;                       // 512 KB
  uint64_t* kbuf = (uint64_t*)((char*)d_ws + (size_t)BATCH * NPTS * sizeof(float4));
                                                        // 8192*20*8B = 1.31 MB

  prep_kernel<<<dim3(BATCH * NPTS / 256), dim3(256), 0, stream>>>(verts, vc);
  knn_scan_kernel<<<dim3(BATCH * QN * SUBS * 64 / SBLOCK), dim3(SBLOCK), 0,
                    stream>>>(vc, sidx, kbuf, outV);
  knn_gather_kernel<<<dim3(BATCH * QN / GQPB), dim3(GBLOCK), 0, stream>>>(
      feat, kbuf, outF);
}